// Round 3
// baseline (1268.969 us; speedup 1.0000x reference)
//
#include <hip/hip_runtime.h>
#include <stdint.h>

#define F 16
#define CDIM 320
#define DDIM 4096
#define NSEQ 8192
#define WPB 4
#define THREADS 256
#define NT 20
#define KS 10

typedef __attribute__((ext_vector_type(8))) short short8;
typedef __attribute__((ext_vector_type(4))) float f32x4;

__device__ __forceinline__ unsigned short f2bf(float f) {
    union { float f; uint32_t u; } v; v.f = f;
    uint32_t r = v.u + 0x7FFFu + ((v.u >> 16) & 1u);   // RTNE
    return (unsigned short)(r >> 16);
}
__device__ __forceinline__ float bf2f(unsigned short h) {
    union { uint32_t u; float f; } v; v.u = ((uint32_t)h) << 16;
    return v.f;
}
// full-row swizzle: [16][320] bf16 tile, stride 640 B (chunk idx 0..39, xor low3)
__device__ __forceinline__ int swz(int row, int b) {
    return row * 640 + (b ^ ((row & 7) << 4));
}
// half-row swizzle: [16][160] bf16 tile, stride 320 B (chunk idx 0..19, xor low2
// only, so swizzled chunk stays < 20)
__device__ __forceinline__ int hswz(int row, int b) {
    return row * 320 + (b ^ ((row & 3) << 4));
}

// One-time: pack Wq/Wk/Wv/Wo (fp32 row-major [320][320]) into bf16 B-fragment
// order. Fragment (m, nt, ks) is a 1KB block: lane (g,lr) holds
// W[nt*16+lr][ks*32+g*8 .. +7]. Byte offset = ((m*NT+nt)*KS+ks)*1024 + lane*16.
__global__ __launch_bounds__(256)
void pack_weights_kernel(const float* __restrict__ Wq, const float* __restrict__ Wk,
                         const float* __restrict__ Wv, const float* __restrict__ Wo,
                         char* __restrict__ pk)
{
    const int t = blockIdx.x * 256 + threadIdx.x;
    if (t >= 4 * NT * KS * 64) return;
    const int lane = t & 63;
    const int rest = t >> 6;
    const int ks = rest % KS;
    const int nt = (rest / KS) % NT;
    const int m  = rest / (KS * NT);
    const float* W = (m == 0) ? Wq : (m == 1) ? Wk : (m == 2) ? Wv : Wo;
    const int g = lane >> 4, lr = lane & 15;
    const float* src = W + (size_t)(nt * 16 + lr) * CDIM + ks * 32 + g * 8;
    const f32x4 a = *(const f32x4*)src;
    const f32x4 b = *(const f32x4*)(src + 4);
    float vals[8] = {a[0], a[1], a[2], a[3], b[0], b[1], b[2], b[3]};
    short8 o;
#pragma unroll
    for (int j = 0; j < 8; ++j) o[j] = (short)f2bf(vals[j]);
    *(short8*)(pk + (size_t)t * 16) = o;
}

__global__ __launch_bounds__(THREADS, 4)
void temporal_attn_kernel(const float* __restrict__ hs,
                          const char* __restrict__ wpk,
                          const float* __restrict__ bo,
                          float* __restrict__ out)
{
    extern __shared__ __align__(16) char smem[];
    // per-wave 10240 B: kb [16][160] bf16 (5120) + vb [16][160] bf16 (5120).
    // After both attention passes, the full 10240 B is reused as the
    // attention-out [16][320] bf16 buffer. No __syncthreads anywhere.
    const int tid  = threadIdx.x;
    const int lane = tid & 63;
    const int wave = tid >> 6;
    const int g    = lane >> 4;
    const int lr   = lane & 15;

    const int seq = blockIdx.x * WPB + wave;
    const int bi  = seq >> 12;
    const int di  = seq & (DDIM - 1);

    char* const kb  = smem + wave * 10240;
    char* const vb  = kb + 5120;
    char* const aob = kb;                 // overlay, used after both passes
    const char* const wl = wpk + lane * 16;

    // ---- load x rows, add PE, convert to bf16 A-fragments ----
    const float* xrow = hs + ((size_t)(bi * F + lr) * DDIM + di) * CDIM;
    short8 axk[KS];
#pragma unroll
    for (int ks = 0; ks < KS; ++ks) {
        const int k0 = ks * 32 + g * 8;
        const f32x4 a = *(const f32x4*)(xrow + k0);
        const f32x4 b = *(const f32x4*)(xrow + k0 + 4);
        float xv[8] = {a[0], a[1], a[2], a[3], b[0], b[1], b[2], b[3]};
#pragma unroll
        for (int jj = 0; jj < 4; ++jj) {
            const float c0 = (float)(k0 + 2 * jj);
            const float dv = __expf(c0 * -0.028782313662425575f); // -ln(1e4)/320
            const float ang = (float)lr * dv;                      // pos = frame
            xv[2 * jj]     += __sinf(ang);
            xv[2 * jj + 1] += __cosf(ang);
        }
        short8 t;
#pragma unroll
        for (int j = 0; j < 8; ++j) t[j] = (short)f2bf(xv[j]);
        axk[ks] = t;
    }

    // half projection: matrix m, head-half h2 (cols 160*h2 .. +159) -> dst
    auto projh = [&](int m, int h2, char* dst) {
#pragma unroll 2
        for (int ntp = 0; ntp < 10; ++ntp) {
            f32x4 acc = {0.f, 0.f, 0.f, 0.f};
#pragma unroll
            for (int ks = 0; ks < KS; ++ks) {
                short8 b = *(const short8*)(wl +
                    (size_t)((m * NT + h2 * 10 + ntp) * KS + ks) * 1024);
                acc = __builtin_amdgcn_mfma_f32_16x16x32_bf16(axk[ks], b, acc, 0, 0, 0);
            }
#pragma unroll
            for (int r = 0; r < 4; ++r)
                *(short*)(dst + hswz(g * 4 + r, (ntp * 16 + lr) * 2)) = (short)f2bf(acc[r]);
        }
    };

    const float scale = 0.15811388300841897f;  // 40^-0.5
    short8 aopk[2][5];

#pragma unroll
    for (int h2 = 0; h2 < 2; ++h2) {
        // Q half -> kb (transient), extract own head's q row to registers
        projh(0, h2, kb);
        float qv[40];
#pragma unroll
        for (int j5 = 0; j5 < 5; ++j5) {
            short8 t = *(const short8*)(kb + hswz(lr, g * 80 + j5 * 16));
#pragma unroll
            for (int j = 0; j < 8; ++j) qv[j5 * 8 + j] = bf2f((unsigned short)t[j]);
        }
        // K half overwrites kb; V half -> vb
        projh(1, h2, kb);
        projh(2, h2, vb);

        // causal attention; lane = (q-row = lr, local head = g)
        float s[F];
#pragma unroll
        for (int kk = 0; kk < F; ++kk) {
            float dot = 0.f;
#pragma unroll
            for (int j5 = 0; j5 < 5; ++j5) {
                short8 t = *(const short8*)(kb + hswz(kk, g * 80 + j5 * 16));
#pragma unroll
                for (int j = 0; j < 8; ++j) dot += qv[j5 * 8 + j] * bf2f((unsigned short)t[j]);
            }
            s[kk] = (kk <= lr) ? dot * scale : -1e30f;
        }
        float m = s[0];
#pragma unroll
        for (int kk = 1; kk < F; ++kk) m = fmaxf(m, s[kk]);
        float p[F]; float sum = 0.f;
#pragma unroll
        for (int kk = 0; kk < F; ++kk) { p[kk] = __expf(s[kk] - m); sum += p[kk]; }
        const float inv = 1.f / sum;
        float acc[40];
#pragma unroll
        for (int dd = 0; dd < 40; ++dd) acc[dd] = 0.f;
#pragma unroll
        for (int kk = 0; kk < F; ++kk) {
            const float pk = p[kk] * inv;
#pragma unroll
            for (int j5 = 0; j5 < 5; ++j5) {
                short8 t = *(const short8*)(vb + hswz(kk, g * 80 + j5 * 16));
#pragma unroll
                for (int j = 0; j < 8; ++j) acc[j5 * 8 + j] += pk * bf2f((unsigned short)t[j]);
            }
        }
        // pack attention-out to bf16 registers (kept until after both passes)
#pragma unroll
        for (int j5 = 0; j5 < 5; ++j5) {
            short8 t;
#pragma unroll
            for (int j = 0; j < 8; ++j) t[j] = (short)f2bf(acc[j5 * 8 + j]);
            aopk[h2][j5] = t;
        }
    }

    // write attention-out into the full [16][320] overlay buffer
#pragma unroll
    for (int h2 = 0; h2 < 2; ++h2)
#pragma unroll
        for (int j5 = 0; j5 < 5; ++j5)
            *(short8*)(aob + swz(lr, (g + 4 * h2) * 80 + j5 * 16)) = aopk[h2][j5];

    // ---- output projection: out = ao @ Wo.T + bo ----
    short8 aof[KS];
#pragma unroll
    for (int ks = 0; ks < KS; ++ks)
        aof[ks] = *(const short8*)(aob + swz(lr, ks * 64 + g * 16));

#pragma unroll 2
    for (int nt = 0; nt < NT; ++nt) {
        f32x4 acc = {0.f, 0.f, 0.f, 0.f};
#pragma unroll
        for (int ks = 0; ks < KS; ++ks) {
            short8 b = *(const short8*)(wl + (size_t)((3 * NT + nt) * KS + ks) * 1024);
            acc = __builtin_amdgcn_mfma_f32_16x16x32_bf16(aof[ks], b, acc, 0, 0, 0);
        }
        const int col = nt * 16 + lr;
        const float bias = bo[col];
#pragma unroll
        for (int r = 0; r < 4; ++r) {
            const int row = g * 4 + r;   // frame index
            out[((size_t)(bi * F + row) * DDIM + di) * CDIM + col] = acc[r] + bias;
        }
    }
}

extern "C" void kernel_launch(void* const* d_in, const int* in_sizes, int n_in,
                              void* d_out, int out_size, void* d_ws, size_t ws_size,
                              hipStream_t stream) {
    const float* hs = (const float*)d_in[0];
    const float* Wq = (const float*)d_in[1];
    const float* Wk = (const float*)d_in[2];
    const float* Wv = (const float*)d_in[3];
    const float* Wo = (const float*)d_in[4];
    const float* bo = (const float*)d_in[5];
    float* out = (float*)d_out;
    char* wpk = (char*)d_ws;   // 4*200*1024 = 819200 B of packed bf16 weights

    pack_weights_kernel<<<dim3((4 * NT * KS * 64 + 255) / 256), dim3(256), 0, stream>>>(
        Wq, Wk, Wv, Wo, wpk);

    const int lds = WPB * 10240;   // 40960 B -> 4 blocks/CU
    (void)hipFuncSetAttribute((const void*)temporal_attn_kernel,
                              hipFuncAttributeMaxDynamicSharedMemorySize, lds);
    temporal_attn_kernel<<<dim3(NSEQ / WPB), dim3(THREADS), lds, stream>>>(
        hs, wpk, bo, out);
}